// Round 1
// baseline (2873.832 us; speedup 1.0000x reference)
//
#include <hip/hip_runtime.h>

typedef unsigned short u16;
typedef unsigned int u32;

typedef __bf16 bf16x8 __attribute__((ext_vector_type(8)));
typedef float f32x4 __attribute__((ext_vector_type(4)));

// ---------------------------------------------------------------------------
// Problem constants
// ---------------------------------------------------------------------------
constexpr int Mdim = 16384;  // batch
constexpr int Ndim = 4096;   // prod(OUT_MODES)
constexpr int Kdim = 4096;   // prod(IN_MODES)

constexpr int BM = 128, BN = 128, BK = 32;
constexpr int NK = Kdim / BK;  // 128 K-steps

// ---------------------------------------------------------------------------
// bf16 helpers (round-to-nearest-even, bit-exact, self-contained)
// ---------------------------------------------------------------------------
__device__ __forceinline__ u32 f2bf_bits(float f) {
  u32 u = __float_as_uint(f);
  return (u + 0x7FFFu + ((u >> 16) & 1u)) >> 16;
}
__device__ __forceinline__ float bf2f(u32 hbits) {
  return __uint_as_float(hbits << 16);
}

// split 8 fp32 -> 8 bf16 hi + 8 bf16 lo (packed as uint4 each)
__device__ __forceinline__ void cvt8(float4 a, float4 b, uint4& h, uint4& l) {
  float v[8] = {a.x, a.y, a.z, a.w, b.x, b.y, b.z, b.w};
  u32 hb[8], lb[8];
#pragma unroll
  for (int j = 0; j < 8; ++j) {
    hb[j] = f2bf_bits(v[j]);
    float r = v[j] - bf2f(hb[j]);
    lb[j] = f2bf_bits(r);
  }
  h.x = hb[0] | (hb[1] << 16); h.y = hb[2] | (hb[3] << 16);
  h.z = hb[4] | (hb[5] << 16); h.w = hb[6] | (hb[7] << 16);
  l.x = lb[0] | (lb[1] << 16); l.y = lb[2] | (lb[3] << 16);
  l.z = lb[4] | (lb[5] << 16); l.w = lb[6] | (lb[7] << 16);
}

__device__ __forceinline__ void gload16(const void* gsrc, void* ldst) {
  __builtin_amdgcn_global_load_lds(
      (__attribute__((address_space(1))) void*)(gsrc),
      (__attribute__((address_space(3))) void*)(ldst), 16, 0, 0);
}

// ---------------------------------------------------------------------------
// Kernel 1: contract TT cores into dense W (4096 x 4096), split hi/lo bf16.
// W[q,p] = sum_{r1,r2,r3} w0[o0*16+r1, i0] * w1[o1*16+r2, r1*8+i1]
//                        * w2[o2*16+r3, r2*8+i2] * w3[o3, r3*8+i3]
// q = o0*512+o1*64+o2*8+o3 ; p = i0*512+i1*64+i2*8+i3
// grid: 512 blocks = (o0, i0, o1); 256 threads.
// ---------------------------------------------------------------------------
__global__ __launch_bounds__(256) void build_w(
    const float* __restrict__ w0, const float* __restrict__ w1,
    const float* __restrict__ w2, const float* __restrict__ w3,
    u16* __restrict__ Whi, u16* __restrict__ Wlo) {
  __shared__ float sw2[128 * 128];
  __shared__ float sw3[8 * 128];
  __shared__ float sA2[8][16];  // [i1][r2] for this (o0,i0,o1)

  const int tid = threadIdx.x;
  const int b = blockIdx.x;
  const int o0 = b >> 6, i0 = (b >> 3) & 7, o1 = b & 7;

  for (int i = tid; i < 128 * 128 / 4; i += 256)
    ((float4*)sw2)[i] = ((const float4*)w2)[i];
  if (tid < 8 * 128 / 4) ((float4*)sw3)[tid] = ((const float4*)w3)[tid];

  if (tid < 128) {
    const int i1 = tid >> 4, r2 = tid & 15;
    float s = 0.f;
#pragma unroll
    for (int r1 = 0; r1 < 16; ++r1)
      s += w0[(o0 * 16 + r1) * 8 + i0] * w1[(o1 * 16 + r2) * 128 + r1 * 8 + i1];
    sA2[i1][r2] = s;
  }
  __syncthreads();

  for (int cc = tid; cc < 512; cc += 256) {  // (i1, o2, i2)
    const int i1 = cc >> 6, o2 = (cc >> 3) & 7, i2 = cc & 7;
    float t3[16];
#pragma unroll
    for (int r3 = 0; r3 < 16; ++r3) {
      float s = 0.f;
#pragma unroll
      for (int r2 = 0; r2 < 16; ++r2)
        s += sA2[i1][r2] * sw2[(o2 * 16 + r3) * 128 + r2 * 8 + i2];
      t3[r3] = s;
    }
    const size_t p0 = (size_t)i0 * 512 + i1 * 64 + i2 * 8;
#pragma unroll
    for (int o3 = 0; o3 < 8; ++o3) {
      u32 hb[8], lb[8];
#pragma unroll
      for (int i3 = 0; i3 < 8; ++i3) {
        float s = 0.f;
#pragma unroll
        for (int r3 = 0; r3 < 16; ++r3)
          s += t3[r3] * sw3[o3 * 128 + r3 * 8 + i3];
        hb[i3] = f2bf_bits(s);
        float r = s - bf2f(hb[i3]);
        lb[i3] = f2bf_bits(r);
      }
      const size_t q = (size_t)o0 * 512 + o1 * 64 + o2 * 8 + o3;
      uint4 hv, lv;
      hv.x = hb[0] | (hb[1] << 16); hv.y = hb[2] | (hb[3] << 16);
      hv.z = hb[4] | (hb[5] << 16); hv.w = hb[6] | (hb[7] << 16);
      lv.x = lb[0] | (lb[1] << 16); lv.y = lb[2] | (lb[3] << 16);
      lv.z = lb[4] | (lb[5] << 16); lv.w = lb[6] | (lb[7] << 16);
      *(uint4*)&Whi[q * (size_t)Kdim + p0] = hv;
      *(uint4*)&Wlo[q * (size_t)Kdim + p0] = lv;
    }
  }
}

// ---------------------------------------------------------------------------
// Kernel 2: y = x . W^T + bias, split-precision bf16x3 MFMA GEMM.
// M=16384, N=4096, K=4096. 128x128 tile, BK=32, 256 thr (4 waves, 2x2),
// each wave owns a 64x64 sub-tile = 4x4 of 16x16x32 bf16 MFMA fragments.
//
// LDS tiles are FRAGMENT-ORDERED: unit u (16 B = one lane's fragment) with
// u = blk16*64 + kgrp*16 + (row|col within 16-block). A lane reading fragment
// `blk16` loads at  base + blk16*1024 + lane*16  -> perfectly linear, zero
// bank conflicts; global_load_lds writes linearly with a pre-permuted global
// source (rule #21); A is reg-staged (fp32 -> hi/lo bf16) with the same
// ordering on the ds_write side.
// ---------------------------------------------------------------------------
__global__ __launch_bounds__(256, 2) void tt_gemm(
    const float* __restrict__ x, const u16* __restrict__ Whi,
    const u16* __restrict__ Wlo, const float* __restrict__ bias,
    float* __restrict__ out) {
  __shared__ u16 sAhi[2][BM * BK], sAlo[2][BM * BK];
  __shared__ u16 sBhi[2][BM * BK], sBlo[2][BM * BK];  // 64 KiB total

  const int tid = threadIdx.x;
  const int lane = tid & 63;
  const int w = tid >> 6;
  const int wr = w >> 1, wc = w & 1;

  // bijective XCD swizzle (nwg=4096, %8==0), then bm-major (A-panel stays in
  // this XCD's L2; W streams from L3).
  const int wg = ((int)blockIdx.x & 7) * 512 + ((int)blockIdx.x >> 3);
  const int bm = wg >> 5;   // 0..127
  const int bn = wg & 31;   // 0..31

  const float* xbase = x + (size_t)bm * BM * Kdim;
  const u16* whbase = Whi + (size_t)bn * BN * Kdim;
  const u16* wlbase = Wlo + (size_t)bn * BN * Kdim;

  // A staging: thread covers units u0, u0+1 (two consecutive rows, same kgrp)
  const int u0 = tid * 2;
  const int amb = u0 >> 6, ag = (u0 >> 4) & 3, ar = u0 & 15;
  const float* asrc0 = xbase + (size_t)(amb * 16 + ar) * Kdim + ag * 8;

  f32x4 acc[4][4];
#pragma unroll
  for (int m = 0; m < 4; ++m)
#pragma unroll
    for (int n = 0; n < 4; ++n)
#pragma unroll
      for (int j = 0; j < 4; ++j) acc[m][n][j] = 0.0f;

  float4 fa0, fa1, fa2, fa3;

  auto loadA = [&](int kt) {
    const float* s = asrc0 + kt * BK;
    fa0 = *(const float4*)(s);
    fa1 = *(const float4*)(s + 4);
    fa2 = *(const float4*)(s + Kdim);
    fa3 = *(const float4*)(s + Kdim + 4);
  };
  auto writeA = [&](int bb) {
    uint4 h, l;
    cvt8(fa0, fa1, h, l);
    *(uint4*)&sAhi[bb][u0 * 8] = h;
    *(uint4*)&sAlo[bb][u0 * 8] = l;
    cvt8(fa2, fa3, h, l);
    *(uint4*)&sAhi[bb][u0 * 8 + 8] = h;
    *(uint4*)&sAlo[bb][u0 * 8 + 8] = l;
  };
  auto stageB = [&](int bb, int kt) {
#pragma unroll
    for (int p = 0; p < 2; ++p) {
      const int u = p * 256 + tid;
      const int nb = u >> 6, g = (u >> 4) & 3, c = u & 15;
      const size_t goff = (size_t)(nb * 16 + c) * Kdim + kt * BK + g * 8;
      gload16(whbase + goff, &sBhi[bb][u * 8]);
      gload16(wlbase + goff, &sBlo[bb][u * 8]);
    }
  };

  // prologue
  loadA(0);
  stageB(0, 0);
  writeA(0);
  __syncthreads();

  int buf = 0;
  for (int kt = 0; kt < NK; ++kt) {
    const int nxt = buf ^ 1;
    const bool more = (kt + 1 < NK);
    if (more) {
      loadA(kt + 1);      // issue global loads early (latency hides under MFMA)
      stageB(nxt, kt + 1);  // async global->LDS, drains at the barrier
    }

    bf16x8 ah[4], al[4], bh[4], bl[4];
#pragma unroll
    for (int i = 0; i < 4; ++i) {
      ah[i] = *(const bf16x8*)&sAhi[buf][(wr * 4 + i) * 512 + lane * 8];
      al[i] = *(const bf16x8*)&sAlo[buf][(wr * 4 + i) * 512 + lane * 8];
      bh[i] = *(const bf16x8*)&sBhi[buf][(wc * 4 + i) * 512 + lane * 8];
      bl[i] = *(const bf16x8*)&sBlo[buf][(wc * 4 + i) * 512 + lane * 8];
    }
    // three split-products, all accumulating into the same acc (K-recipe)
#pragma unroll
    for (int m = 0; m < 4; ++m)
#pragma unroll
      for (int n = 0; n < 4; ++n)
        acc[m][n] = __builtin_amdgcn_mfma_f32_16x16x32_bf16(ah[m], bh[n],
                                                            acc[m][n], 0, 0, 0);
#pragma unroll
    for (int m = 0; m < 4; ++m)
#pragma unroll
      for (int n = 0; n < 4; ++n)
        acc[m][n] = __builtin_amdgcn_mfma_f32_16x16x32_bf16(ah[m], bl[n],
                                                            acc[m][n], 0, 0, 0);
#pragma unroll
    for (int m = 0; m < 4; ++m)
#pragma unroll
      for (int n = 0; n < 4; ++n)
        acc[m][n] = __builtin_amdgcn_mfma_f32_16x16x32_bf16(al[m], bh[n],
                                                            acc[m][n], 0, 0, 0);

    if (more) writeA(nxt);  // compiler inserts vmcnt wait before the cvt
    __syncthreads();
    buf = nxt;
  }

  // epilogue: C/D layout col=lane&15, row=(lane>>4)*4+reg (m89/m91)
  const int r4 = (lane >> 4) * 4;
  const int ccol = lane & 15;
#pragma unroll
  for (int m = 0; m < 4; ++m) {
    const int grow = bm * BM + wr * 64 + m * 16 + r4;
#pragma unroll
    for (int n = 0; n < 4; ++n) {
      const int gcol = bn * BN + wc * 64 + n * 16 + ccol;
      const float bv = bias[gcol];
      float* o = out + (size_t)grow * Ndim + gcol;
#pragma unroll
      for (int j = 0; j < 4; ++j) o[(size_t)j * Ndim] = acc[m][n][j] + bv;
    }
  }
}

// ---------------------------------------------------------------------------
extern "C" void kernel_launch(void* const* d_in, const int* in_sizes, int n_in,
                              void* d_out, int out_size, void* d_ws,
                              size_t ws_size, hipStream_t stream) {
  const float* x = (const float*)d_in[0];
  const float* w0 = (const float*)d_in[1];
  const float* w1 = (const float*)d_in[2];
  const float* w2 = (const float*)d_in[3];
  const float* w3 = (const float*)d_in[4];
  const float* bias = (const float*)d_in[5];
  float* out = (float*)d_out;

  u16* Whi = (u16*)d_ws;                       // 4096*4096 bf16 = 33.5 MB
  u16* Wlo = Whi + (size_t)Ndim * Kdim;        // another 33.5 MB

  build_w<<<dim3(512), dim3(256), 0, stream>>>(w0, w1, w2, w3, Whi, Wlo);
  tt_gemm<<<dim3(4096), dim3(256), 0, stream>>>(x, Whi, Wlo, bias, out);
}

// Round 2
// 1446.663 us; speedup vs baseline: 1.9865x; 1.9865x over previous
//
#include <hip/hip_runtime.h>

typedef unsigned short u16;
typedef unsigned int u32;
typedef _Float16 f16;
typedef f16 f16x8 __attribute__((ext_vector_type(8)));
typedef float f32x4 __attribute__((ext_vector_type(4)));

// ---------------------------------------------------------------------------
// Problem constants
// ---------------------------------------------------------------------------
constexpr int Mdim = 16384;  // batch
constexpr int Ndim = 4096;   // prod(OUT_MODES)
constexpr int Kdim = 4096;   // prod(IN_MODES)

constexpr int BM = 128, BN = 128, BK = 32;
constexpr int NK = Kdim / BK;  // 128 K-steps

// fp32 -> fp16 (RNE via v_cvt_f16_f32), return raw bits
__device__ __forceinline__ u32 f2h(float f) {
  f16 h = (f16)f;
  union { f16 h; u16 u; } c;
  c.h = h;
  return (u32)c.u;
}

__device__ __forceinline__ void gload16(const void* gsrc, void* ldst) {
  __builtin_amdgcn_global_load_lds(
      (__attribute__((address_space(1))) void*)(gsrc),
      (__attribute__((address_space(3))) void*)(ldst), 16, 0, 0);
}

// ---------------------------------------------------------------------------
// Kernel 1: x (fp32, 16384x4096) -> xh (fp16 bits), row-major. BW-bound.
// ---------------------------------------------------------------------------
__global__ __launch_bounds__(256) void cvt_x(const float* __restrict__ x,
                                             u16* __restrict__ xh) {
  const int n8 = Mdim * Kdim / 8;  // 8.39M units of 8 elems
  for (int i = blockIdx.x * 256 + threadIdx.x; i < n8; i += gridDim.x * 256) {
    float4 a = ((const float4*)x)[2 * i];
    float4 b = ((const float4*)x)[2 * i + 1];
    uint4 o;
    o.x = f2h(a.x) | (f2h(a.y) << 16);
    o.y = f2h(a.z) | (f2h(a.w) << 16);
    o.z = f2h(b.x) | (f2h(b.y) << 16);
    o.w = f2h(b.z) | (f2h(b.w) << 16);
    ((uint4*)xh)[i] = o;
  }
}

// ---------------------------------------------------------------------------
// Kernel 2: contract TT cores into dense W (4096 x 4096) in fp16.
// W[q,p] = sum_{r1,r2,r3} w0[o0*16+r1, i0] * w1[o1*16+r2, r1*8+i1]
//                        * w2[o2*16+r3, r2*8+i2] * w3[o3, r3*8+i3]
// q = o0*512+o1*64+o2*8+o3 ; p = i0*512+i1*64+i2*8+i3
// grid: 512 blocks = (o0, i0, o1); 256 threads.  (indexing verified: passed R1)
// ---------------------------------------------------------------------------
__global__ __launch_bounds__(256) void build_w(
    const float* __restrict__ w0, const float* __restrict__ w1,
    const float* __restrict__ w2, const float* __restrict__ w3,
    u16* __restrict__ Wh) {
  __shared__ float sw2[128 * 128];
  __shared__ float sw3[8 * 128];
  __shared__ float sA2[8][16];  // [i1][r2] for this (o0,i0,o1)

  const int tid = threadIdx.x;
  const int b = blockIdx.x;
  const int o0 = b >> 6, i0 = (b >> 3) & 7, o1 = b & 7;

  for (int i = tid; i < 128 * 128 / 4; i += 256)
    ((float4*)sw2)[i] = ((const float4*)w2)[i];
  if (tid < 8 * 128 / 4) ((float4*)sw3)[tid] = ((const float4*)w3)[tid];

  if (tid < 128) {
    const int i1 = tid >> 4, r2 = tid & 15;
    float s = 0.f;
#pragma unroll
    for (int r1 = 0; r1 < 16; ++r1)
      s += w0[(o0 * 16 + r1) * 8 + i0] * w1[(o1 * 16 + r2) * 128 + r1 * 8 + i1];
    sA2[i1][r2] = s;
  }
  __syncthreads();

  for (int cc = tid; cc < 512; cc += 256) {  // (i1, o2, i2)
    const int i1 = cc >> 6, o2 = (cc >> 3) & 7, i2 = cc & 7;
    float t3[16];
#pragma unroll
    for (int r3 = 0; r3 < 16; ++r3) {
      float s = 0.f;
#pragma unroll
      for (int r2 = 0; r2 < 16; ++r2)
        s += sA2[i1][r2] * sw2[(o2 * 16 + r3) * 128 + r2 * 8 + i2];
      t3[r3] = s;
    }
    const size_t p0 = (size_t)i0 * 512 + i1 * 64 + i2 * 8;
#pragma unroll
    for (int o3 = 0; o3 < 8; ++o3) {
      u32 hb[8];
#pragma unroll
      for (int i3 = 0; i3 < 8; ++i3) {
        float s = 0.f;
#pragma unroll
        for (int r3 = 0; r3 < 16; ++r3)
          s += t3[r3] * sw3[o3 * 128 + r3 * 8 + i3];
        hb[i3] = f2h(s);
      }
      const size_t q = (size_t)o0 * 512 + o1 * 64 + o2 * 8 + o3;
      uint4 hv;
      hv.x = hb[0] | (hb[1] << 16);
      hv.y = hb[2] | (hb[3] << 16);
      hv.z = hb[4] | (hb[5] << 16);
      hv.w = hb[6] | (hb[7] << 16);
      *(uint4*)&Wh[q * (size_t)Kdim + p0] = hv;
    }
  }
}

// ---------------------------------------------------------------------------
// Kernel 3: y = xh . Wh^T + bias, single-pass fp16 MFMA GEMM.
// M=16384, N=4096, K=4096. 128x128 tile, BK=32, 256 thr (4 waves, 2x2),
// each wave owns a 64x64 sub-tile = 4x4 of 16x16x32 f16 MFMA fragments.
//
// LDS tiles FRAGMENT-ORDERED: unit u (16 B = one lane's k-fragment) with
// u = blk16*64 + kgrp*16 + r16. Both A and B staged with global_load_lds
// (width 16) from per-lane permuted global addresses (rule #21); LDS dest
// is linear (wave-uniform base + lane*16). ds_read_b128 at base+lane*16 ->
// zero bank conflicts. No in-loop VALU conversion (R1's writeA eliminated).
// ---------------------------------------------------------------------------
__global__ __launch_bounds__(256, 4) void tt_gemm(
    const u16* __restrict__ xh, const u16* __restrict__ Wh,
    const float* __restrict__ bias, float* __restrict__ out) {
  __shared__ u16 sA[2][BM * BK], sB[2][BN * BK];  // 32 KiB total

  const int tid = threadIdx.x;
  const int lane = tid & 63;
  const int w = tid >> 6;
  const int wr = w >> 1, wc = w & 1;

  // bijective XCD swizzle (nwg=4096, %8==0), then bm-major: the 32 blocks of
  // one bm-group run near-in-time on one XCD -> A-panel (1 MB fp16) L2-hits;
  // W (33 MB fp16) streams from L3.
  const int wg = ((int)blockIdx.x & 7) * 512 + ((int)blockIdx.x >> 3);
  const int bm = wg >> 5;  // 0..127
  const int bn = wg & 31;  // 0..31

  const u16* abase = xh + (size_t)bm * BM * Kdim;
  const u16* bbase = Wh + (size_t)bn * BN * Kdim;

  // staging: 512 units per tile, 2 per thread. unit u -> row blk*16+r16,
  // k-offset g*8 within the BK=32 slab.
  const int ua = tid, ub = tid + 256;
  const size_t ga0 = (size_t)((ua >> 6) * 16 + (ua & 15)) * Kdim + ((ua >> 4) & 3) * 8;
  const size_t ga1 = (size_t)((ub >> 6) * 16 + (ub & 15)) * Kdim + ((ub >> 4) & 3) * 8;

  f32x4 acc[4][4];
#pragma unroll
  for (int m = 0; m < 4; ++m)
#pragma unroll
    for (int n = 0; n < 4; ++n)
#pragma unroll
      for (int j = 0; j < 4; ++j) acc[m][n][j] = 0.0f;

  auto stage = [&](int bb, int kt) {
    const size_t ko = (size_t)kt * BK;
    gload16(abase + ga0 + ko, &sA[bb][ua * 8]);
    gload16(abase + ga1 + ko, &sA[bb][ub * 8]);
    gload16(bbase + ga0 + ko, &sB[bb][ua * 8]);
    gload16(bbase + ga1 + ko, &sB[bb][ub * 8]);
  };

  // prologue
  stage(0, 0);
  __syncthreads();  // compiler drains vmcnt before barrier

  int buf = 0;
  for (int kt = 0; kt < NK; ++kt) {
    const int nxt = buf ^ 1;
    if (kt + 1 < NK) stage(nxt, kt + 1);  // issue early; drains at barrier

    f16x8 a[4], b[4];
#pragma unroll
    for (int i = 0; i < 4; ++i) {
      a[i] = *(const f16x8*)&sA[buf][(wr * 4 + i) * 512 + lane * 8];
      b[i] = *(const f16x8*)&sB[buf][(wc * 4 + i) * 512 + lane * 8];
    }
#pragma unroll
    for (int m = 0; m < 4; ++m)
#pragma unroll
      for (int n = 0; n < 4; ++n)
        acc[m][n] = __builtin_amdgcn_mfma_f32_16x16x32_f16(a[m], b[n],
                                                           acc[m][n], 0, 0, 0);
    __syncthreads();
    buf = nxt;
  }

  // epilogue: C/D layout col=lane&15, row=(lane>>4)*4+reg (m89/m91; verified
  // in R1's passing kernel)
  const int r4 = (lane >> 4) * 4;
  const int ccol = lane & 15;
#pragma unroll
  for (int m = 0; m < 4; ++m) {
    const int grow = bm * BM + wr * 64 + m * 16 + r4;
#pragma unroll
    for (int n = 0; n < 4; ++n) {
      const int gcol = bn * BN + wc * 64 + n * 16 + ccol;
      const float bv = bias[gcol];
      float* o = out + (size_t)grow * Ndim + gcol;
#pragma unroll
      for (int j = 0; j < 4; ++j) o[(size_t)j * Ndim] = acc[m][n][j] + bv;
    }
  }
}

// ---------------------------------------------------------------------------
extern "C" void kernel_launch(void* const* d_in, const int* in_sizes, int n_in,
                              void* d_out, int out_size, void* d_ws,
                              size_t ws_size, hipStream_t stream) {
  const float* x = (const float*)d_in[0];
  const float* w0 = (const float*)d_in[1];
  const float* w1 = (const float*)d_in[2];
  const float* w2 = (const float*)d_in[3];
  const float* w3 = (const float*)d_in[4];
  const float* bias = (const float*)d_in[5];
  float* out = (float*)d_out;

  u16* Wh = (u16*)d_ws;                        // 4096*4096 fp16 = 33.5 MB
  u16* xh = Wh + (size_t)Ndim * Kdim;          // 16384*4096 fp16 = 134 MB

  cvt_x<<<dim3(2048), dim3(256), 0, stream>>>(x, xh);
  build_w<<<dim3(512), dim3(256), 0, stream>>>(w0, w1, w2, w3, Wh);
  tt_gemm<<<dim3(4096), dim3(256), 0, stream>>>(xh, Wh, bias, out);
}

// Round 3
// 1341.260 us; speedup vs baseline: 2.1426x; 1.0786x over previous
//
#include <hip/hip_runtime.h>

typedef unsigned short u16;
typedef unsigned int u32;
typedef _Float16 f16;
typedef f16 f16x8 __attribute__((ext_vector_type(8)));
typedef float f32x4 __attribute__((ext_vector_type(4)));

// ---------------------------------------------------------------------------
// Problem constants
// ---------------------------------------------------------------------------
constexpr int Mdim = 16384;  // batch
constexpr int Ndim = 4096;   // prod(OUT_MODES)
constexpr int Kdim = 4096;   // prod(IN_MODES)

constexpr int BM = 256, BN = 256, BK = 32;
constexpr int NK = Kdim / BK;  // 128 K-slabs

// fp32 -> fp16 (RNE via v_cvt_f16_f32), return raw bits
__device__ __forceinline__ u32 f2h(float f) {
  f16 h = (f16)f;
  union { f16 h; u16 u; } c;
  c.h = h;
  return (u32)c.u;
}

__device__ __forceinline__ void gload16(const void* gsrc, void* ldst) {
  __builtin_amdgcn_global_load_lds(
      (__attribute__((address_space(1))) void*)(gsrc),
      (__attribute__((address_space(3))) void*)(ldst), 16, 0, 0);
}

// ---------------------------------------------------------------------------
// Kernel 1: x (fp32, 16384x4096) -> xh (fp16 bits), row-major. BW-bound.
// ---------------------------------------------------------------------------
__global__ __launch_bounds__(256) void cvt_x(const float* __restrict__ x,
                                             u16* __restrict__ xh) {
  const int n8 = Mdim * Kdim / 8;
  for (int i = blockIdx.x * 256 + threadIdx.x; i < n8; i += gridDim.x * 256) {
    float4 a = ((const float4*)x)[2 * i];
    float4 b = ((const float4*)x)[2 * i + 1];
    uint4 o;
    o.x = f2h(a.x) | (f2h(a.y) << 16);
    o.y = f2h(a.z) | (f2h(a.w) << 16);
    o.z = f2h(b.x) | (f2h(b.y) << 16);
    o.w = f2h(b.z) | (f2h(b.w) << 16);
    ((uint4*)xh)[i] = o;
  }
}

// ---------------------------------------------------------------------------
// Kernel 2: contract TT cores into dense W (4096 x 4096) in fp16.
// (indexing verified: passed R1/R2)
// ---------------------------------------------------------------------------
__global__ __launch_bounds__(256) void build_w(
    const float* __restrict__ w0, const float* __restrict__ w1,
    const float* __restrict__ w2, const float* __restrict__ w3,
    u16* __restrict__ Wh) {
  __shared__ float sw2[128 * 128];
  __shared__ float sw3[8 * 128];
  __shared__ float sA2[8][16];

  const int tid = threadIdx.x;
  const int b = blockIdx.x;
  const int o0 = b >> 6, i0 = (b >> 3) & 7, o1 = b & 7;

  for (int i = tid; i < 128 * 128 / 4; i += 256)
    ((float4*)sw2)[i] = ((const float4*)w2)[i];
  if (tid < 8 * 128 / 4) ((float4*)sw3)[tid] = ((const float4*)w3)[tid];

  if (tid < 128) {
    const int i1 = tid >> 4, r2 = tid & 15;
    float s = 0.f;
#pragma unroll
    for (int r1 = 0; r1 < 16; ++r1)
      s += w0[(o0 * 16 + r1) * 8 + i0] * w1[(o1 * 16 + r2) * 128 + r1 * 8 + i1];
    sA2[i1][r2] = s;
  }
  __syncthreads();

  for (int cc = tid; cc < 512; cc += 256) {  // (i1, o2, i2)
    const int i1 = cc >> 6, o2 = (cc >> 3) & 7, i2 = cc & 7;
    float t3[16];
#pragma unroll
    for (int r3 = 0; r3 < 16; ++r3) {
      float s = 0.f;
#pragma unroll
      for (int r2 = 0; r2 < 16; ++r2)
        s += sA2[i1][r2] * sw2[(o2 * 16 + r3) * 128 + r2 * 8 + i2];
      t3[r3] = s;
    }
    const size_t p0 = (size_t)i0 * 512 + i1 * 64 + i2 * 8;
#pragma unroll
    for (int o3 = 0; o3 < 8; ++o3) {
      u32 hb[8];
#pragma unroll
      for (int i3 = 0; i3 < 8; ++i3) {
        float s = 0.f;
#pragma unroll
        for (int r3 = 0; r3 < 16; ++r3)
          s += t3[r3] * sw3[o3 * 128 + r3 * 8 + i3];
        hb[i3] = f2h(s);
      }
      const size_t q = (size_t)o0 * 512 + o1 * 64 + o2 * 8 + o3;
      uint4 hv;
      hv.x = hb[0] | (hb[1] << 16);
      hv.y = hb[2] | (hb[3] << 16);
      hv.z = hb[4] | (hb[5] << 16);
      hv.w = hb[6] | (hb[7] << 16);
      *(uint4*)&Wh[q * (size_t)Kdim + p0] = hv;
    }
  }
}

// ---------------------------------------------------------------------------
// Kernel 3: y = xh . Wh^T + bias. 256x256 tile, BK=32, 512 thr (8 waves,
// 2M x 4N; per-wave 128x64 = 8x4 fragments of 16x16x32).
//
// Counted-vmcnt ring pipeline (T3+T4): 4 LDS slots (A+B, 128 KiB), slabs
// staged 3 deep via global_load_lds; per K-step ONE raw s_barrier and ONE
// s_waitcnt vmcnt(8) -- loads stay in flight across barriers (never drain
// to 0 in the main loop). Invariants:
//   - stage(t+3) -> slot (t-1)&3: its previous occupant (slab t-1) was read
//     in iter t-1, strictly before barrier(t); stage is issued after
//     barrier(t) => no overwrite race (cross-wave via barrier semantics).
//   - vmcnt(8) at iter t leaves slabs {t+1,t+2} (8 loads) outstanding =>
//     slab t's 4 loads (oldest) have landed; barrier(t) publishes this
//     wave's landing to all waves before any wave reads slab t.
//   - tail: vmcnt(4) at t=NK-2, vmcnt(0) at t=NK-1.
// LDS is FRAGMENT-ORDERED (16B unit per lane) => ds_read_b128 and
// global_load_lds are both linear: 0 bank conflicts (measured R2).
// ---------------------------------------------------------------------------
__global__ __launch_bounds__(512, 2) void tt_gemm(
    const u16* __restrict__ xh, const u16* __restrict__ Wh,
    const float* __restrict__ bias, float* __restrict__ out) {
  __shared__ u16 sA[4][8192];  // 4 slots x (16 mb-blocks x 64 lanes x 8 f16)
  __shared__ u16 sB[4][8192];  // = 4 x 16 KiB each; 128 KiB total

  const int tid = threadIdx.x;
  const int lane = tid & 63;
  const int w = tid >> 6;        // 0..7
  const int wm = w >> 2;         // 0..1  (row half)
  const int wn = w & 3;          // 0..3  (col quarter)

  // bijective XCD swizzle (nwg=1024 % 8 == 0); bm-major within an XCD:
  // 32 co-resident blocks = 2 bm-groups x 16 bn -> two 2MB A-panels L2-hit,
  // W (33 MB) streams from L3.
  const int wg = ((int)blockIdx.x & 7) * 128 + ((int)blockIdx.x >> 3);
  const int bm = wg >> 4;  // 0..63
  const int bn = wg & 15;  // 0..15

  const u16* abase = xh + (size_t)bm * BM * Kdim;
  const u16* bbase = Wh + (size_t)bn * BN * Kdim;

  // staging: wave w stages mb/nb blocks {2w, 2w+1}; one gload16 per block
  // covers 16 rows x 32k (each row's full 64B slab via lanes {r,r+16,r+32,r+48}).
  const int r15 = lane & 15, g = lane >> 4;
  const size_t ga0 = (size_t)((2 * w + 0) * 16 + r15) * Kdim + g * 8;
  const size_t ga1 = (size_t)((2 * w + 1) * 16 + r15) * Kdim + g * 8;
  const int lu0 = ((2 * w + 0) * 64 + lane) * 8;
  const int lu1 = ((2 * w + 1) * 64 + lane) * 8;

  auto stage = [&](int slot, int t) {
    const size_t ko = (size_t)t * BK;
    gload16(abase + ga0 + ko, &sA[slot][lu0]);
    gload16(abase + ga1 + ko, &sA[slot][lu1]);
    gload16(bbase + ga0 + ko, &sB[slot][lu0]);
    gload16(bbase + ga1 + ko, &sB[slot][lu1]);
  };

  f32x4 acc[8][4];
#pragma unroll
  for (int m = 0; m < 8; ++m)
#pragma unroll
    for (int n = 0; n < 4; ++n)
#pragma unroll
      for (int j = 0; j < 4; ++j) acc[m][n][j] = 0.0f;

  // prologue: 3 slabs in flight
  stage(0, 0);
  stage(1, 1);
  stage(2, 2);

  for (int t = 0; t < NK; ++t) {
    if (t < NK - 2)
      asm volatile("s_waitcnt vmcnt(8)" ::: "memory");
    else if (t == NK - 2)
      asm volatile("s_waitcnt vmcnt(4)" ::: "memory");
    else
      asm volatile("s_waitcnt vmcnt(0)" ::: "memory");
    __builtin_amdgcn_s_barrier();
    asm volatile("" ::: "memory");  // pin LDS reads below the barrier

    if (t + 3 < NK) stage((t + 3) & 3, t + 3);

    const int slot = t & 3;
    f16x8 a[8], b[4];
#pragma unroll
    for (int m = 0; m < 8; ++m)
      a[m] = *(const f16x8*)&sA[slot][((wm * 8 + m) * 64 + lane) * 8];
#pragma unroll
    for (int n = 0; n < 4; ++n)
      b[n] = *(const f16x8*)&sB[slot][((wn * 4 + n) * 64 + lane) * 8];

    __builtin_amdgcn_s_setprio(1);
#pragma unroll
    for (int m = 0; m < 8; ++m)
#pragma unroll
      for (int n = 0; n < 4; ++n)
        acc[m][n] = __builtin_amdgcn_mfma_f32_16x16x32_f16(a[m], b[n],
                                                           acc[m][n], 0, 0, 0);
    __builtin_amdgcn_s_setprio(0);
  }

  // epilogue: C/D layout col=lane&15, row=(lane>>4)*4+reg (verified R1/R2)
  const int r4 = g * 4;
#pragma unroll
  for (int m = 0; m < 8; ++m) {
    const int grow = bm * BM + wm * 128 + m * 16 + r4;
#pragma unroll
    for (int n = 0; n < 4; ++n) {
      const int gcol = bn * BN + wn * 64 + n * 16 + r15;
      const float bv = bias[gcol];
      float* o = out + (size_t)grow * Ndim + gcol;
#pragma unroll
      for (int j = 0; j < 4; ++j) o[(size_t)j * Ndim] = acc[m][n][j] + bv;
    }
  }
}

// ---------------------------------------------------------------------------
extern "C" void kernel_launch(void* const* d_in, const int* in_sizes, int n_in,
                              void* d_out, int out_size, void* d_ws,
                              size_t ws_size, hipStream_t stream) {
  const float* x = (const float*)d_in[0];
  const float* w0 = (const float*)d_in[1];
  const float* w1 = (const float*)d_in[2];
  const float* w2 = (const float*)d_in[3];
  const float* w3 = (const float*)d_in[4];
  const float* bias = (const float*)d_in[5];
  float* out = (float*)d_out;

  u16* Wh = (u16*)d_ws;                  // 4096*4096 fp16 = 33.5 MB
  u16* xh = Wh + (size_t)Ndim * Kdim;    // 16384*4096 fp16 = 134 MB

  cvt_x<<<dim3(4096), dim3(256), 0, stream>>>(x, xh);
  build_w<<<dim3(512), dim3(256), 0, stream>>>(w0, w1, w2, w3, Wh);
  tt_gemm<<<dim3(1024), dim3(512), 0, stream>>>(xh, Wh, bias, out);
}